// Round 13
// baseline (617.295 us; speedup 1.0000x reference)
//
#include <hip/hip_runtime.h>
#include <hip/hip_bf16.h>

typedef __bf16 bfv8 __attribute__((ext_vector_type(8)));
typedef float f32x4 __attribute__((ext_vector_type(4)));
typedef float fv4 __attribute__((ext_vector_type(4)));
typedef unsigned int u32;
typedef unsigned short ush;

#define MFMA(a,b,c) __builtin_amdgcn_mfma_f32_16x16x32_bf16((a),(b),(c),0,0,0)

constexpr int XW_LD = 392;   // 384+8 pad

// Transposed bf16 weights: qT[col][k] = w_qkv[k][col], pT[col][k] = w_proj[k][col]
__global__ __launch_bounds__(256)
void prep_weights(const float* __restrict__ w_qkv, const float* __restrict__ w_proj,
                  ush* __restrict__ qT, ush* __restrict__ pT)
{
    int i = blockIdx.x * 256 + threadIdx.x;
    const int NQ = 1152 * 384;
    if (i < NQ) {
        int c = i / 384, k = i - c * 384;
        __bf16 h = (__bf16)w_qkv[k * 1152 + c];
        qT[i] = *(ush*)&h;
    } else {
        int j = i - NQ;
        if (j < 384 * 384) {
            int c = j / 384, k = j - c * 384;
            __bf16 h = (__bf16)w_proj[k * 384 + c];
            pT[j] = *(ush*)&h;
        }
    }
}

__device__ __forceinline__ u32 pkbf(float a, float b) {
    __bf16 x = (__bf16)a, y = (__bf16)b;
    ush lo = *(ush*)&x, hi = *(ush*)&y;
    return ((u32)hi << 16) | lo;
}

// Universal D-frag -> A/B-frag converter (HW-verified rounds 3-12)
__device__ __forceinline__ bfv8 conv_frag(u32 p00, u32 p01, u32 p10, u32 p11,
                                          int abase, bool selhi)
{
    union { u32 u[4]; bfv8 v; } cv;
    #pragma unroll
    for (int w = 0; w < 4; ++w) {
        const int addr = abase + (w >> 1) * 64;
        const int lo_ = __builtin_amdgcn_ds_bpermute(addr, (int)((w & 1) ? p01 : p00));
        const int hi_ = __builtin_amdgcn_ds_bpermute(addr, (int)((w & 1) ? p11 : p10));
        cv.u[w] = (u32)(selhi ? hi_ : lo_);
    }
    return cv.v;
}

// ============ Kernel A: QKV + attention, O -> global bf16 (natural rows) ======
// 384 thr = 6 waves per window; 2 heads/wave; LDS 50KB -> 3 WG/CU = 18 waves/CU
// at <=102 VGPR (launch_bounds(384,5)). qt-streamed softmax keeps st to 16 regs;
// pkK/pkV converted to frags immediately (never >1 pk set + kf + Vf live).
__global__ __launch_bounds__(384, 5)
void qkv_attn(const float* __restrict__ x,
              const float* __restrict__ b_qkv,
              const ush* __restrict__ qT_,
              ush* __restrict__ O_)
{
    __shared__ __bf16 sX[64 * XW_LD];   // 50176 B

    const __bf16* wqkvT = (const __bf16*)qT_;
    const int wid  = blockIdx.x;
    const int bb   = wid >> 6;
    const int wy   = (wid >> 3) & 7;
    const int wx   = wid & 7;
    const int tid  = threadIdx.x;
    const int lane = tid & 63;
    const int wv   = tid >> 6;          // wave 0..5
    const int lr   = lane & 15;
    const int lg   = lane >> 4;
    const int k8   = lg * 8;

    const size_t gbase   = ((size_t)(bb * 64 + wy * 8) * 64 + wx * 8) * 384;
    const int    rowbase = bb * 4096 + wy * 512 + wx * 8;   // natural row of token 0

    // ---- stage x window -> sX bf16 ----
    {
        const float* xb = x + gbase;
        for (int i = tid; i < 64 * 96; i += 384) {
            int t  = i / 96;
            int c4 = (i - t * 96) * 4;
            const fv4 v = __builtin_nontemporal_load(
                (const fv4*)(xb + (size_t)((t >> 3) * 64 + (t & 7)) * 384 + c4));
            *(uint2*)&sX[t * XW_LD + c4] = make_uint2(pkbf(v.x, v.y), pkbf(v.z, v.w));
        }
    }
    __syncthreads();   // the only barrier

    const int   abase = ((lg & 1) * 32 + lr) * 4;
    const bool  selhi = (lg & 2) != 0;
    const float SC    = 0.17677669529663687f;
    const __bf16* xp  = &sX[lr * XW_LD + k8];

    #pragma unroll 1
    for (int hl = 0; hl < 2; ++hl) {
        const int h  = wv * 2 + hl;
        const int cQ = h * 32, cK = cQ + 384, cV = cQ + 768;

        u32  pkQ[2][4][2];
        bfv8 kf[4];
        bfv8 Vf[2][2];

        // ---- pass 1: Q^T = mfma(Wq, x); keep packed ----
        {
            float bQ0[2][4];
            #pragma unroll
            for (int hdt = 0; hdt < 2; ++hdt)
                #pragma unroll
                for (int r = 0; r < 4; ++r) bQ0[hdt][r] = b_qkv[cQ + hdt * 16 + lg * 4 + r];
            f32x4 acc[2][4];
            #pragma unroll
            for (int a = 0; a < 2; ++a)
                #pragma unroll
                for (int b = 0; b < 4; ++b) acc[a][b] = f32x4{0,0,0,0};
            const __bf16* wp = wqkvT + (size_t)(cQ + lr) * 384 + k8;
            #pragma unroll 4
            for (int kk = 0; kk < 12; ++kk) {
                bfv8 xf[4], wf[2];
                #pragma unroll
                for (int t4 = 0; t4 < 4; ++t4) xf[t4] = *(const bfv8*)(xp + t4 * 16 * XW_LD + kk * 32);
                #pragma unroll
                for (int hdt = 0; hdt < 2; ++hdt) wf[hdt] = *(const bfv8*)(wp + (size_t)hdt * 16 * 384 + kk * 32);
                #pragma unroll
                for (int hdt = 0; hdt < 2; ++hdt)
                    #pragma unroll
                    for (int t4 = 0; t4 < 4; ++t4)
                        acc[hdt][t4] = MFMA(wf[hdt], xf[t4], acc[hdt][t4]);
            }
            #pragma unroll
            for (int hdt = 0; hdt < 2; ++hdt)
                #pragma unroll
                for (int t4 = 0; t4 < 4; ++t4) {
                    pkQ[hdt][t4][0] = pkbf((acc[hdt][t4][0] + bQ0[hdt][0]) * SC, (acc[hdt][t4][1] + bQ0[hdt][1]) * SC);
                    pkQ[hdt][t4][1] = pkbf((acc[hdt][t4][2] + bQ0[hdt][2]) * SC, (acc[hdt][t4][3] + bQ0[hdt][3]) * SC);
                }
        }

        // ---- pass 2: K^T = mfma(Wk, x); convert straight to kf[4] ----
        {
            float bK0[2][4];
            #pragma unroll
            for (int hdt = 0; hdt < 2; ++hdt)
                #pragma unroll
                for (int r = 0; r < 4; ++r) bK0[hdt][r] = b_qkv[cK + hdt * 16 + lg * 4 + r];
            f32x4 acc[2][4];
            #pragma unroll
            for (int a = 0; a < 2; ++a)
                #pragma unroll
                for (int b = 0; b < 4; ++b) acc[a][b] = f32x4{0,0,0,0};
            const __bf16* wp = wqkvT + (size_t)(cK + lr) * 384 + k8;
            #pragma unroll 4
            for (int kk = 0; kk < 12; ++kk) {
                bfv8 xf[4], wf[2];
                #pragma unroll
                for (int t4 = 0; t4 < 4; ++t4) xf[t4] = *(const bfv8*)(xp + t4 * 16 * XW_LD + kk * 32);
                #pragma unroll
                for (int hdt = 0; hdt < 2; ++hdt) wf[hdt] = *(const bfv8*)(wp + (size_t)hdt * 16 * 384 + kk * 32);
                #pragma unroll
                for (int hdt = 0; hdt < 2; ++hdt)
                    #pragma unroll
                    for (int t4 = 0; t4 < 4; ++t4)
                        acc[hdt][t4] = MFMA(wf[hdt], xf[t4], acc[hdt][t4]);
            }
            u32 pkK[2][4][2];
            #pragma unroll
            for (int hdt = 0; hdt < 2; ++hdt)
                #pragma unroll
                for (int t4 = 0; t4 < 4; ++t4) {
                    pkK[hdt][t4][0] = pkbf(acc[hdt][t4][0] + bK0[hdt][0], acc[hdt][t4][1] + bK0[hdt][1]);
                    pkK[hdt][t4][1] = pkbf(acc[hdt][t4][2] + bK0[hdt][2], acc[hdt][t4][3] + bK0[hdt][3]);
                }
            #pragma unroll
            for (int kt = 0; kt < 4; ++kt)
                kf[kt] = conv_frag(pkK[0][kt][0], pkK[0][kt][1], pkK[1][kt][0], pkK[1][kt][1], abase, selhi);
        }

        // ---- pass 3: V = mfma(x, Wv); convert straight to Vf[2][2] ----
        {
            float bV0[2];
            #pragma unroll
            for (int hdt = 0; hdt < 2; ++hdt) bV0[hdt] = b_qkv[cV + hdt * 16 + lr];
            f32x4 acc[4][2];
            #pragma unroll
            for (int a = 0; a < 4; ++a)
                #pragma unroll
                for (int b = 0; b < 2; ++b) acc[a][b] = f32x4{0,0,0,0};
            const __bf16* wp = wqkvT + (size_t)(cV + lr) * 384 + k8;
            #pragma unroll 4
            for (int kk = 0; kk < 12; ++kk) {
                bfv8 xf[4], wf[2];
                #pragma unroll
                for (int t4 = 0; t4 < 4; ++t4) xf[t4] = *(const bfv8*)(xp + t4 * 16 * XW_LD + kk * 32);
                #pragma unroll
                for (int hdt = 0; hdt < 2; ++hdt) wf[hdt] = *(const bfv8*)(wp + (size_t)hdt * 16 * 384 + kk * 32);
                #pragma unroll
                for (int t4 = 0; t4 < 4; ++t4)
                    #pragma unroll
                    for (int hdt = 0; hdt < 2; ++hdt)
                        acc[t4][hdt] = MFMA(xf[t4], wf[hdt], acc[t4][hdt]);
            }
            u32 pkV[4][2][2];
            #pragma unroll
            for (int hdt = 0; hdt < 2; ++hdt)
                #pragma unroll
                for (int t4 = 0; t4 < 4; ++t4) {
                    pkV[t4][hdt][0] = pkbf(acc[t4][hdt][0] + bV0[hdt], acc[t4][hdt][1] + bV0[hdt]);
                    pkV[t4][hdt][1] = pkbf(acc[t4][hdt][2] + bV0[hdt], acc[t4][hdt][3] + bV0[hdt]);
                }
            #pragma unroll
            for (int ks = 0; ks < 2; ++ks)
                #pragma unroll
                for (int hdt = 0; hdt < 2; ++hdt)
                    Vf[ks][hdt] = conv_frag(pkV[2 * ks][hdt][0], pkV[2 * ks][hdt][1],
                                            pkV[2 * ks + 1][hdt][0], pkV[2 * ks + 1][hdt][1], abase, selhi);
        }

        // ---- attention, qt-streamed: st is 16 regs, O stored per qt ----
        #pragma unroll
        for (int qt = 0; qt < 4; ++qt) {
            const bfv8 Qf = conv_frag(pkQ[0][qt][0], pkQ[0][qt][1], pkQ[1][qt][0], pkQ[1][qt][1], abase, selhi);
            f32x4 st[4];
            #pragma unroll
            for (int kt = 0; kt < 4; ++kt) {
                f32x4 z{};
                st[kt] = MFMA(kf[kt], Qf, z);
            }
            float mx = -1e30f;
            #pragma unroll
            for (int kt = 0; kt < 4; ++kt)
                #pragma unroll
                for (int r = 0; r < 4; ++r) mx = fmaxf(mx, st[kt][r]);
            mx = fmaxf(mx, __shfl_xor(mx, 16, 64));
            mx = fmaxf(mx, __shfl_xor(mx, 32, 64));
            float sum = 0.f;
            #pragma unroll
            for (int kt = 0; kt < 4; ++kt)
                #pragma unroll
                for (int r = 0; r < 4; ++r) { st[kt][r] = __expf(st[kt][r] - mx); sum += st[kt][r]; }
            sum += __shfl_xor(sum, 16, 64);
            sum += __shfl_xor(sum, 32, 64);
            const float rinv = 1.f / sum;
            u32 pkP[4][2];
            #pragma unroll
            for (int kt = 0; kt < 4; ++kt) {
                pkP[kt][0] = pkbf(st[kt][0] * rinv, st[kt][1] * rinv);
                pkP[kt][1] = pkbf(st[kt][2] * rinv, st[kt][3] * rinv);
            }
            const bfv8 pf0 = conv_frag(pkP[0][0], pkP[0][1], pkP[1][0], pkP[1][1], abase, selhi);
            const bfv8 pf1 = conv_frag(pkP[2][0], pkP[2][1], pkP[3][0], pkP[3][1], abase, selhi);
            f32x4 o0{}, o1{};
            o0 = MFMA(pf0, Vf[0][0], o0);
            o0 = MFMA(pf1, Vf[1][0], o0);
            o1 = MFMA(pf0, Vf[0][1], o1);
            o1 = MFMA(pf1, Vf[1][1], o1);
            // store O rows (natural order); 16 lanes x 2B = 32B contiguous chunks
            #pragma unroll
            for (int r = 0; r < 4; ++r) {
                const int t    = qt * 16 + lg * 4 + r;
                const int nrow = rowbase + (t >> 3) * 64 + (t & 7);
                __bf16 a0 = (__bf16)o0[r], a1 = (__bf16)o1[r];
                O_[(size_t)nrow * 384 + cQ + lr]      = *(ush*)&a0;
                O_[(size_t)nrow * 384 + cQ + 16 + lr] = *(ush*)&a1;
            }
        }
    }
}

// ============ Kernel B: proj GEMM, O(131072x384 bf16) @ Wp + b -> out fp32 ====
// 8192 independent waves (2048 WGs x 4); wave = 64 rows x 96 cols (acc[4][6]).
// No LDS, no barriers; A rows + B cols read from global (L2/L3-resident).
__global__ __launch_bounds__(256, 3)
void proj_gemm(const ush* __restrict__ O_,
               const ush* __restrict__ pT_,
               const float* __restrict__ b_proj,
               float* __restrict__ out)
{
    const __bf16* Ob = (const __bf16*)O_;
    const __bf16* wprojT = (const __bf16*)pT_;
    const int tid  = threadIdx.x;
    const int lane = tid & 63;
    const int wv   = tid >> 6;
    const int lr   = lane & 15;
    const int lg   = lane >> 4;
    const int k8   = lg * 8;
    const int g    = blockIdx.x * 4 + wv;   // 0..8191
    const int row0 = (g >> 2) * 64;
    const int nb   = (g & 3) * 96;

    const __bf16* ap = Ob + (size_t)(row0 + lr) * 384 + k8;
    const __bf16* bp = wprojT + (size_t)(nb + lr) * 384 + k8;

    f32x4 acc[4][6];
    #pragma unroll
    for (int m = 0; m < 4; ++m)
        #pragma unroll
        for (int nt = 0; nt < 6; ++nt) acc[m][nt] = f32x4{0,0,0,0};

    #pragma unroll 3
    for (int kk = 0; kk < 12; ++kk) {
        bfv8 bfr[6];
        #pragma unroll
        for (int nt = 0; nt < 6; ++nt)
            bfr[nt] = *(const bfv8*)(bp + (size_t)nt * 16 * 384 + kk * 32);
        #pragma unroll
        for (int m = 0; m < 4; ++m) {
            const bfv8 af = *(const bfv8*)(ap + (size_t)m * 16 * 384 + kk * 32);
            #pragma unroll
            for (int nt = 0; nt < 6; ++nt)
                acc[m][nt] = MFMA(af, bfr[nt], acc[m][nt]);
        }
    }

    float bpj[6];
    #pragma unroll
    for (int nt = 0; nt < 6; ++nt) bpj[nt] = b_proj[nb + nt * 16 + lr];
    #pragma unroll
    for (int m = 0; m < 4; ++m)
        #pragma unroll
        for (int r = 0; r < 4; ++r) {
            float* op = out + (size_t)(row0 + m * 16 + lg * 4 + r) * 384 + nb;
            #pragma unroll
            for (int nt = 0; nt < 6; ++nt)
                op[nt * 16 + lr] = acc[m][nt][r] + bpj[nt];
        }
}

// ============ Fallback: R12 fused kernel (used if ws too small) ==============
__global__ __launch_bounds__(256, 3)
void win_attn(const float* __restrict__ x,
              const float* __restrict__ b_qkv,
              const float* __restrict__ b_proj,
              const ush* __restrict__ qT_,
              const ush* __restrict__ pT_,
              float* __restrict__ out)
{
    __shared__ __bf16 sX[64 * XW_LD];
    const __bf16* wqkvT  = (const __bf16*)qT_;
    const __bf16* wprojT = (const __bf16*)pT_;
    const int wid  = blockIdx.x;
    const int bb   = wid >> 6;
    const int wy   = (wid >> 3) & 7;
    const int wx   = wid & 7;
    const int tid  = threadIdx.x;
    const int lane = tid & 63;
    const int wv   = tid >> 6;
    const int lr   = lane & 15;
    const int lg   = lane >> 4;
    const int k8   = lg * 8;
    const size_t gbase = ((size_t)(bb * 64 + wy * 8) * 64 + wx * 8) * 384;
    {
        const float* xb = x + gbase;
        for (int i = tid; i < 64 * 96; i += 256) {
            int t  = i / 96;
            int c4 = (i - t * 96) * 4;
            const fv4 v = *(const fv4*)(xb + (size_t)((t >> 3) * 64 + (t & 7)) * 384 + c4);
            *(uint2*)&sX[t * XW_LD + c4] = make_uint2(pkbf(v.x, v.y), pkbf(v.z, v.w));
        }
    }
    __syncthreads();
    const int   abase = ((lg & 1) * 32 + lr) * 4;
    const bool  selhi = (lg & 2) != 0;
    const float SC    = 0.17677669529663687f;
    u32 opk[3][4][2][2];
    #pragma unroll
    for (int hl = 0; hl < 3; ++hl) {
        const int h  = wv * 3 + hl;
        const int cQ = h * 32, cK = cQ + 384, cV = cQ + 768;
        const __bf16* xp = &sX[lr * XW_LD + k8];
        float bQ0[2][4], bK0[2][4], bV0[2];
        #pragma unroll
        for (int hdt = 0; hdt < 2; ++hdt) {
            #pragma unroll
            for (int r = 0; r < 4; ++r) {
                bQ0[hdt][r] = b_qkv[cQ + hdt * 16 + lg * 4 + r];
                bK0[hdt][r] = b_qkv[cK + hdt * 16 + lg * 4 + r];
            }
            bV0[hdt] = b_qkv[cV + hdt * 16 + lr];
        }
        u32 pkQ[2][4][2], pkK[2][4][2], pkV[4][2][2];
        {
            f32x4 acc[2][4];
            #pragma unroll
            for (int a = 0; a < 2; ++a)
                #pragma unroll
                for (int b = 0; b < 4; ++b) acc[a][b] = f32x4{0,0,0,0};
            const __bf16* wp = wqkvT + (size_t)(cQ + lr) * 384 + k8;
            #pragma unroll 6
            for (int kk = 0; kk < 12; ++kk) {
                bfv8 xf[4], wf[2];
                #pragma unroll
                for (int t4 = 0; t4 < 4; ++t4) xf[t4] = *(const bfv8*)(xp + t4 * 16 * XW_LD + kk * 32);
                #pragma unroll
                for (int hdt = 0; hdt < 2; ++hdt) wf[hdt] = *(const bfv8*)(wp + (size_t)hdt * 16 * 384 + kk * 32);
                #pragma unroll
                for (int hdt = 0; hdt < 2; ++hdt)
                    #pragma unroll
                    for (int t4 = 0; t4 < 4; ++t4)
                        acc[hdt][t4] = MFMA(wf[hdt], xf[t4], acc[hdt][t4]);
            }
            #pragma unroll
            for (int hdt = 0; hdt < 2; ++hdt)
                #pragma unroll
                for (int t4 = 0; t4 < 4; ++t4) {
                    pkQ[hdt][t4][0] = pkbf((acc[hdt][t4][0] + bQ0[hdt][0]) * SC, (acc[hdt][t4][1] + bQ0[hdt][1]) * SC);
                    pkQ[hdt][t4][1] = pkbf((acc[hdt][t4][2] + bQ0[hdt][2]) * SC, (acc[hdt][t4][3] + bQ0[hdt][3]) * SC);
                }
        }
        {
            f32x4 acc[2][4];
            #pragma unroll
            for (int a = 0; a < 2; ++a)
                #pragma unroll
                for (int b = 0; b < 4; ++b) acc[a][b] = f32x4{0,0,0,0};
            const __bf16* wp = wqkvT + (size_t)(cK + lr) * 384 + k8;
            #pragma unroll 6
            for (int kk = 0; kk < 12; ++kk) {
                bfv8 xf[4], wf[2];
                #pragma unroll
                for (int t4 = 0; t4 < 4; ++t4) xf[t4] = *(const bfv8*)(xp + t4 * 16 * XW_LD + kk * 32);
                #pragma unroll
                for (int hdt = 0; hdt < 2; ++hdt) wf[hdt] = *(const bfv8*)(wp + (size_t)hdt * 16 * 384 + kk * 32);
                #pragma unroll
                for (int hdt = 0; hdt < 2; ++hdt)
                    #pragma unroll
                    for (int t4 = 0; t4 < 4; ++t4)
                        acc[hdt][t4] = MFMA(wf[hdt], xf[t4], acc[hdt][t4]);
            }
            #pragma unroll
            for (int hdt = 0; hdt < 2; ++hdt)
                #pragma unroll
                for (int t4 = 0; t4 < 4; ++t4) {
                    pkK[hdt][t4][0] = pkbf(acc[hdt][t4][0] + bK0[hdt][0], acc[hdt][t4][1] + bK0[hdt][1]);
                    pkK[hdt][t4][1] = pkbf(acc[hdt][t4][2] + bK0[hdt][2], acc[hdt][t4][3] + bK0[hdt][3]);
                }
        }
        {
            f32x4 acc[4][2];
            #pragma unroll
            for (int a = 0; a < 4; ++a)
                #pragma unroll
                for (int b = 0; b < 2; ++b) acc[a][b] = f32x4{0,0,0,0};
            const __bf16* wp = wqkvT + (size_t)(cV + lr) * 384 + k8;
            #pragma unroll 6
            for (int kk = 0; kk < 12; ++kk) {
                bfv8 xf[4], wf[2];
                #pragma unroll
                for (int t4 = 0; t4 < 4; ++t4) xf[t4] = *(const bfv8*)(xp + t4 * 16 * XW_LD + kk * 32);
                #pragma unroll
                for (int hdt = 0; hdt < 2; ++hdt) wf[hdt] = *(const bfv8*)(wp + (size_t)hdt * 16 * 384 + kk * 32);
                #pragma unroll
                for (int t4 = 0; t4 < 4; ++t4)
                    #pragma unroll
                    for (int hdt = 0; hdt < 2; ++hdt)
                        acc[t4][hdt] = MFMA(xf[t4], wf[hdt], acc[t4][hdt]);
            }
            #pragma unroll
            for (int hdt = 0; hdt < 2; ++hdt) {
                const float bv = bV0[hdt];
                #pragma unroll
                for (int t4 = 0; t4 < 4; ++t4) {
                    pkV[t4][hdt][0] = pkbf(acc[t4][hdt][0] + bv, acc[t4][hdt][1] + bv);
                    pkV[t4][hdt][1] = pkbf(acc[t4][hdt][2] + bv, acc[t4][hdt][3] + bv);
                }
            }
        }
        bfv8 Qf[4];
        #pragma unroll
        for (int qt = 0; qt < 4; ++qt)
            Qf[qt] = conv_frag(pkQ[0][qt][0], pkQ[0][qt][1], pkQ[1][qt][0], pkQ[1][qt][1], abase, selhi);
        f32x4 st[4][4];
        #pragma unroll
        for (int kt = 0; kt < 4; ++kt) {
            const bfv8 kfr = conv_frag(pkK[0][kt][0], pkK[0][kt][1], pkK[1][kt][0], pkK[1][kt][1], abase, selhi);
            #pragma unroll
            for (int qt = 0; qt < 4; ++qt) {
                f32x4 z{};
                st[kt][qt] = MFMA(kfr, Qf[qt], z);
            }
        }
        float rinv[4];
        #pragma unroll
        for (int qt = 0; qt < 4; ++qt) {
            float mx = -1e30f;
            #pragma unroll
            for (int kt = 0; kt < 4; ++kt)
                #pragma unroll
                for (int r = 0; r < 4; ++r) mx = fmaxf(mx, st[kt][qt][r]);
            mx = fmaxf(mx, __shfl_xor(mx, 16, 64));
            mx = fmaxf(mx, __shfl_xor(mx, 32, 64));
            float sum = 0.f;
            #pragma unroll
            for (int kt = 0; kt < 4; ++kt)
                #pragma unroll
                for (int r = 0; r < 4; ++r) { st[kt][qt][r] = __expf(st[kt][qt][r] - mx); sum += st[kt][qt][r]; }
            sum += __shfl_xor(sum, 16, 64);
            sum += __shfl_xor(sum, 32, 64);
            rinv[qt] = 1.f / sum;
        }
        u32 pkP[4][4][2];
        #pragma unroll
        for (int qt = 0; qt < 4; ++qt)
            #pragma unroll
            for (int kt = 0; kt < 4; ++kt)
                #pragma unroll
                for (int p = 0; p < 2; ++p)
                    pkP[qt][kt][p] = pkbf(st[kt][qt][2 * p] * rinv[qt], st[kt][qt][2 * p + 1] * rinv[qt]);
        bfv8 Vf[2][2];
        #pragma unroll
        for (int ks = 0; ks < 2; ++ks)
            #pragma unroll
            for (int hdt = 0; hdt < 2; ++hdt)
                Vf[ks][hdt] = conv_frag(pkV[2 * ks][hdt][0], pkV[2 * ks][hdt][1],
                                        pkV[2 * ks + 1][hdt][0], pkV[2 * ks + 1][hdt][1], abase, selhi);
        #pragma unroll
        for (int qt = 0; qt < 4; ++qt) {
            bfv8 pf0 = conv_frag(pkP[qt][0][0], pkP[qt][0][1], pkP[qt][1][0], pkP[qt][1][1], abase, selhi);
            bfv8 pf1 = conv_frag(pkP[qt][2][0], pkP[qt][2][1], pkP[qt][3][0], pkP[qt][3][1], abase, selhi);
            f32x4 o0{}, o1{};
            o0 = MFMA(pf0, Vf[0][0], o0);
            o0 = MFMA(pf1, Vf[1][0], o0);
            o1 = MFMA(pf0, Vf[0][1], o1);
            o1 = MFMA(pf1, Vf[1][1], o1);
            opk[hl][qt][0][0] = pkbf(o0[0], o0[1]);
            opk[hl][qt][0][1] = pkbf(o0[2], o0[3]);
            opk[hl][qt][1][0] = pkbf(o1[0], o1[1]);
            opk[hl][qt][1][1] = pkbf(o1[2], o1[3]);
        }
    }
    __syncthreads();
    #pragma unroll
    for (int hl = 0; hl < 3; ++hl)
        #pragma unroll
        for (int qt = 0; qt < 4; ++qt)
            #pragma unroll
            for (int hdt = 0; hdt < 2; ++hdt)
                #pragma unroll
                for (int p = 0; p < 2; ++p) {
                    const u32 u = opk[hl][qt][hdt][p];
                    const int row0 = qt * 16 + lg * 4 + 2 * p;
                    const int col  = (wv * 3 + hl) * 32 + hdt * 16 + lr;
                    ush lo = (ush)(u & 0xffff);
                    ush hi = (ush)(u >> 16);
                    sX[row0 * XW_LD + col]       = *(__bf16*)&lo;
                    sX[(row0 + 1) * XW_LD + col] = *(__bf16*)&hi;
                }
    __syncthreads();
    const int nb = wv * 96;
    float bpj[6];
    #pragma unroll
    for (int nt = 0; nt < 6; ++nt) bpj[nt] = b_proj[nb + nt * 16 + lr];
    f32x4 acc[4][6];
    {
        const __bf16* bp = wprojT + (size_t)(nb + lr) * 384 + k8;
        #pragma unroll
        for (int m = 0; m < 4; ++m)
            #pragma unroll
            for (int nt = 0; nt < 6; ++nt) acc[m][nt] = f32x4{0,0,0,0};
        #pragma unroll 2
        for (int kk = 0; kk < 12; ++kk) {
            bfv8 bfr[6];
            #pragma unroll
            for (int nt = 0; nt < 6; ++nt)
                bfr[nt] = *(const bfv8*)(bp + (size_t)nt * 16 * 384 + kk * 32);
            #pragma unroll
            for (int m = 0; m < 4; ++m) {
                const bfv8 af = *(const bfv8*)&sX[(m * 16 + lr) * XW_LD + kk * 32 + k8];
                #pragma unroll
                for (int nt = 0; nt < 6; ++nt)
                    acc[m][nt] = MFMA(af, bfr[nt], acc[m][nt]);
            }
        }
    }
    __syncthreads();
    float* sF = (float*)sX;
    float* ob = out + gbase;
    #pragma unroll
    for (int half = 0; half < 2; ++half) {
        #pragma unroll
        for (int mm = 0; mm < 2; ++mm) {
            const int m = half * 2 + mm;
            #pragma unroll
            for (int r = 0; r < 4; ++r) {
                const int row = mm * 16 + lg * 4 + r;
                #pragma unroll
                for (int nt = 0; nt < 6; ++nt)
                    sF[row * 384 + nb + nt * 16 + lr] = acc[m][nt][r] + bpj[nt];
            }
        }
        __syncthreads();
        for (int i = tid; i < 32 * 96; i += 256) {
            const int row = i / 96;
            const int c4  = (i - row * 96) * 4;
            const int t   = half * 32 + row;
            const fv4 v = *(const fv4*)&sF[row * 384 + c4];
            __builtin_nontemporal_store(v, (fv4*)(ob + (size_t)((t >> 3) * 64 + (t & 7)) * 384 + c4));
        }
        if (half == 0) __syncthreads();
    }
}

extern "C" void kernel_launch(void* const* d_in, const int* in_sizes, int n_in,
                              void* d_out, int out_size, void* d_ws, size_t ws_size,
                              hipStream_t stream)
{
    const float* x      = (const float*)d_in[0];
    const float* w_qkv  = (const float*)d_in[1];
    const float* b_qkv  = (const float*)d_in[2];
    const float* w_proj = (const float*)d_in[3];
    const float* b_proj = (const float*)d_in[4];
    float* out = (float*)d_out;

    ush* qT = (ush*)d_ws;                     // 442368 ush
    ush* pT = qT + 442368;                    // 147456 ush
    ush* O  = pT + 147456;                    // 50331648 ush (100.7 MB)
    const size_t need = (size_t)(442368 + 147456 + 50331648) * 2;

    const int NPREP = 1152 * 384 + 384 * 384;
    prep_weights<<<(NPREP + 255) / 256, 256, 0, stream>>>(w_qkv, w_proj, qT, pT);

    if (ws_size >= need) {
        qkv_attn<<<2048, 384, 0, stream>>>(x, b_qkv, qT, O);
        proj_gemm<<<2048, 256, 0, stream>>>(O, pT, b_proj, out);
    } else {
        win_attn<<<2048, 256, 0, stream>>>(x, b_qkv, b_proj, qT, pT, out);
    }
}